// Round 9
// baseline (181.591 us; speedup 1.0000x reference)
//
#include <hip/hip_runtime.h>
#include <math.h>

// Problem constants (B=4, S=2048, D_MODEL=512, H=8, DQ=64)
#define BATCH 4
#define SEQ   2048
#define DM    512
#define NH    8
#define DQ    64
#define BS    (BATCH*SEQ)     // 8192 rows

// q pre-scale: 1/sqrt(64) * log2(e), so softmax uses native 2^x (v_exp_f32)
#define QSCALE 0.18033688011112042f

typedef short  short8   __attribute__((ext_vector_type(8)));
typedef float  floatx4  __attribute__((ext_vector_type(4)));
typedef float  floatx16 __attribute__((ext_vector_type(16)));
typedef unsigned short ushort8 __attribute__((ext_vector_type(8)));
typedef unsigned uintx2 __attribute__((ext_vector_type(2)));
typedef unsigned uintx4 __attribute__((ext_vector_type(4)));

// cheap bf16: round-half-up (1 add + shift). Ties-only delta vs RNE.
__device__ __forceinline__ unsigned short f2bf(float f) {
    return (unsigned short)((__float_as_uint(f) + 0x8000u) >> 16);
}
// pack two floats -> two bf16 in one u32 (lo = a, hi = b): 2 adds + 1 v_perm
__device__ __forceinline__ unsigned pack2bf(float a, float b) {
    unsigned ua = __float_as_uint(a) + 0x8000u;
    unsigned ub = __float_as_uint(b) + 0x8000u;
    return __builtin_amdgcn_perm(ub, ua, 0x07060302u);  // {ub[3],ub[2],ua[3],ua[2]}
}
// HW packed f32->2xbf16 (RNE), 1 VALU op: lo = cvt(a), hi = cvt(b)
__device__ __forceinline__ unsigned cvtpk(float a, float b) {
    unsigned r;
    asm("v_cvt_pk_bf16_f32 %0, %1, %2" : "=v"(r) : "v"(a), "v"(b));
    return r;
}
// async global->LDS DMA, 16B/lane: lds gets wave-uniform base + lane*16,
// global source is per-lane.
__device__ __forceinline__ void gload16(const unsigned short* g, unsigned short* l) {
    __builtin_amdgcn_global_load_lds(
        (const __attribute__((address_space(1))) unsigned int*)g,
        (__attribute__((address_space(3))) unsigned int*)l, 16, 0, 0);
}

// ---------------------------------------------------------------------------
// convert_w (v12): COALESCED reads for the qkv projections. grid (256, 4).
// ---------------------------------------------------------------------------
__global__ __launch_bounds__(256) void convert_w_kernel(
    const float* __restrict__ Wq, const float* __restrict__ Wk,
    const float* __restrict__ Wv, const float* __restrict__ Wo,
    unsigned short* __restrict__ wt, unsigned short* __restrict__ wo)
{
    const int which = blockIdx.y;
    const int idx = blockIdx.x * 256 + threadIdx.x;   // 65536 per matrix
    if (which == 3) {
        float4 v = *(const float4*)(Wo + (size_t)idx * 4);
        uint2 o;
        o.x = pack2bf(v.x, v.y);
        o.y = pack2bf(v.z, v.w);
        *(uint2*)(wo + (size_t)idx * 4) = o;
    } else {
        const float* W = (which == 0) ? Wq : (which == 1) ? Wk : Wv;
        const int n   = idx & 511;         // h*64+d  (consecutive per lane)
        const int dd0 = (idx >> 9) * 4;    // 0..508
        const int h = n >> 6, d = n & 63;
        uint2 o;
        o.x = pack2bf(W[((size_t)h * DM + dd0 + 0) * DQ + d],
                      W[((size_t)h * DM + dd0 + 1) * DQ + d]);
        o.y = pack2bf(W[((size_t)h * DM + dd0 + 2) * DQ + d],
                      W[((size_t)h * DM + dd0 + 3) * DQ + d]);
        *(uint2*)(wt + (size_t)which * (DM * DM) + (size_t)n * DM + dd0) = o;
    }
}

// ---------------------------------------------------------------------------
// x_convert (NEW v15): Xq/Xk/Xv fp32 -> bf16 once (same f2bf rounding as the
// old in-GEMM pack -> bit-identical results). Enables global_load_lds staging
// in qkv_gemm. 72 MB traffic ~= 12 us. grid (2048, 3).
// ---------------------------------------------------------------------------
__global__ __launch_bounds__(256) void x_convert_kernel(
    const float* __restrict__ Xq, const float* __restrict__ Xk,
    const float* __restrict__ Xv, unsigned short* __restrict__ xb)
{
    const int which = blockIdx.y;
    const float* X = (which == 0) ? Xq : (which == 1) ? Xk : Xv;
    const size_t i = ((size_t)blockIdx.x * 256 + threadIdx.x) * 8;
    const float4 a = *(const float4*)(X + i);
    const float4 b = *(const float4*)(X + i + 4);
    uint4 o;
    o.x = pack2bf(a.x, a.y); o.y = pack2bf(a.z, a.w);
    o.z = pack2bf(b.x, b.y); o.w = pack2bf(b.z, b.w);
    *(uint4*)(xb + (size_t)which * ((size_t)BS * DM) + i) = o;
}

// ---------------------------------------------------------------------------
// qkv GEMM v15: m97 structure. 128x128 tile, BK=64, K=512 (8 k-steps).
// Both A (xb bf16) and B (wt bf16) staged via global_load_lds width=16
// (Common-mistake #1: compiler never auto-emits it; m97 ladder 517->874 TF).
// LDS linear [128][64] (no pad legal for DMA); bank conflicts avoided per
// rule #21: inverse-swizzled global SOURCE (lane l reads col (l&7)^(l>>3))
// + XOR on ds_read (col8 ^ (qr&7)*8) -> LDS[r][c] = G[r][c^(r&7)], frag
// reads spread over 8 slots (2-way = free, m136). 2-barrier k-loop.
// Epilogues unchanged from v11/v12 (q direct, Kf/Vf fragment-major).
// grid (64, 4, 3), block 256 (4 waves 2x2, wave tile 64x64). LDS 32 KB.
// ---------------------------------------------------------------------------
__global__ __launch_bounds__(256) void qkv_gemm_kernel(
    const unsigned short* __restrict__ xb, const unsigned short* __restrict__ wt,
    unsigned short* __restrict__ Oq, unsigned short* __restrict__ Ok,
    unsigned short* __restrict__ Ovt)
{
    __shared__ unsigned short As[128][64];
    __shared__ unsigned short Bs[128][64];

    const int which = blockIdx.z;
    const unsigned short* A  = xb + (size_t)which * ((size_t)BS * DM);
    const unsigned short* Bt = wt + (size_t)which * (DM * DM);

    const int m0 = blockIdx.x * 128;
    const int n0 = blockIdx.y * 128;
    const int t = threadIdx.x, w = t >> 6, lane = t & 63;
    const int quad = lane >> 4, qr = lane & 15;
    const int mw = 64 * (w >> 1), nw = 64 * (w & 1);

    // per-lane DMA source offset: row lr within 8-row block, swizzled 16B slot
    const int lr = lane >> 3;
    const int swoff = (((lane & 7) ^ lr) * 8) + lr * DM;   // ushorts

    floatx4 acc[4][4] = {};

    for (int k0 = 0; k0 < DM; k0 += 64) {
        if (k0) __syncthreads();          // prior reads done before overwrite
        #pragma unroll
        for (int c = 0; c < 4; ++c) {
            const int rb = 8 * (w + 4 * c);
            gload16(A  + (size_t)(m0 + rb) * DM + k0 + swoff, &As[rb][0]);
            gload16(Bt + (size_t)(n0 + rb) * DM + k0 + swoff, &Bs[rb][0]);
        }
        __syncthreads();                  // vmcnt drain + visibility

        #pragma unroll
        for (int kh = 0; kh < 2; ++kh) {
            const int cs = (kh * 32 + quad * 8) ^ ((qr & 7) * 8);
            short8 af[4], bf[4];
            #pragma unroll
            for (int si = 0; si < 4; ++si)
                af[si] = *(const short8*)&As[mw + 16 * si + qr][cs];
            #pragma unroll
            for (int sj = 0; sj < 4; ++sj)
                bf[sj] = *(const short8*)&Bs[nw + 16 * sj + qr][cs];
            #pragma unroll
            for (int si = 0; si < 4; ++si)
                #pragma unroll
                for (int sj = 0; sj < 4; ++sj)
                    acc[si][sj] = __builtin_amdgcn_mfma_f32_16x16x32_bf16(
                        af[si], bf[sj], acc[si][sj], 0, 0, 0);
        }
    }

    if (which == 0) {
        #pragma unroll
        for (int si = 0; si < 4; ++si) {
            #pragma unroll
            for (int sj = 0; sj < 4; ++sj) {
                const int col = n0 + nw + 16 * sj + qr;
                const int h = col >> 6, d = col & 63;
                #pragma unroll
                for (int r = 0; r < 4; ++r) {
                    const int row = m0 + mw + 16 * si + quad * 4 + r;
                    const int b = row >> 11, s = row & (SEQ - 1);
                    Oq[((size_t)(b * NH + h) * SEQ + s) * DQ + d] = f2bf(acc[si][sj][r] * QSCALE);
                }
            }
        }
    } else if (which == 1) {
        #pragma unroll
        for (int si = 0; si < 4; ++si) {
            #pragma unroll
            for (int sj = 0; sj < 4; ++sj) {
                const int col = n0 + nw + 16 * sj + qr;
                const int h = col >> 6, d = col & 63;
                #pragma unroll
                for (int r = 0; r < 4; ++r) {
                    const int row = m0 + mw + 16 * si + quad * 4 + r;
                    const int b = row >> 11, s = row & (SEQ - 1);
                    // Kf fragment-major
                    Ok[(size_t)(b * NH + h) * (SEQ * DQ)
                       + (size_t)(((s >> 5) * 4 + (d >> 4)) << 9)
                       + ((((d >> 3) & 1) << 5) + (s & 31)) * 8 + (d & 7)] = f2bf(acc[si][sj][r]);
                }
            }
        }
    } else {
        #pragma unroll
        for (int si = 0; si < 4; ++si) {
            #pragma unroll
            for (int sj = 0; sj < 4; ++sj) {
                const int col = n0 + nw + 16 * sj + qr;
                const int h = col >> 6, d = col & 63;
                #pragma unroll
                for (int r = 0; r < 4; ++r) {
                    const int row = m0 + mw + 16 * si + quad * 4 + r;
                    const int b = row >> 11, s = row & (SEQ - 1);
                    // Vf fragment-major
                    Ovt[(size_t)(b * NH + h) * (SEQ * DQ)
                        + (size_t)((s >> 6) << 12) + (((s >> 5) & 1) << 11)
                        + ((d >> 5) << 10) + (((s >> 4) & 1) << 9)
                        + ((((s >> 3) & 1) << 5) + (d & 31)) * 8 + (s & 7)] = f2bf(acc[si][sj][r]);
                }
            }
        }
    }
}

// ---------------------------------------------------------------------------
// out GEMM v15: same m97 structure. 64x128 tile, grid (128,4) = 512 blocks
// (2/CU), LDS 24 KB. A = heads bf16 (flat view), B = Wout bf16 B^T.
// ---------------------------------------------------------------------------
__global__ __launch_bounds__(256) void out_gemm_kernel(
    const unsigned short* __restrict__ A, const unsigned short* __restrict__ Bt,
    float* __restrict__ C)
{
    __shared__ unsigned short As[64][64];
    __shared__ unsigned short Bs[128][64];

    const int m0 = blockIdx.x * 64;
    const int n0 = blockIdx.y * 128;
    const int t = threadIdx.x, w = t >> 6, lane = t & 63;
    const int quad = lane >> 4, qr = lane & 15;
    const int mw = 32 * (w >> 1), nw = 64 * (w & 1);

    const int lr = lane >> 3;
    const int swoff = (((lane & 7) ^ lr) * 8) + lr * DM;   // ushorts

    floatx4 acc[2][4] = {};

    for (int k0 = 0; k0 < DM; k0 += 64) {
        if (k0) __syncthreads();
        #pragma unroll
        for (int c = 0; c < 2; ++c) {
            const int rb = 8 * (w + 4 * c);
            gload16(A + (size_t)(m0 + rb) * DM + k0 + swoff, &As[rb][0]);
        }
        #pragma unroll
        for (int c = 0; c < 4; ++c) {
            const int rb = 8 * (w + 4 * c);
            gload16(Bt + (size_t)(n0 + rb) * DM + k0 + swoff, &Bs[rb][0]);
        }
        __syncthreads();

        #pragma unroll
        for (int kh = 0; kh < 2; ++kh) {
            const int cs = (kh * 32 + quad * 8) ^ ((qr & 7) * 8);
            short8 af[2], bf[4];
            #pragma unroll
            for (int si = 0; si < 2; ++si)
                af[si] = *(const short8*)&As[mw + 16 * si + qr][cs];
            #pragma unroll
            for (int sj = 0; sj < 4; ++sj)
                bf[sj] = *(const short8*)&Bs[nw + 16 * sj + qr][cs];
            #pragma unroll
            for (int si = 0; si < 2; ++si)
                #pragma unroll
                for (int sj = 0; sj < 4; ++sj)
                    acc[si][sj] = __builtin_amdgcn_mfma_f32_16x16x32_bf16(
                        af[si], bf[sj], acc[si][sj], 0, 0, 0);
        }
    }

    #pragma unroll
    for (int si = 0; si < 2; ++si) {
        #pragma unroll
        for (int sj = 0; sj < 4; ++sj) {
            const int col = n0 + nw + 16 * sj + qr;
            #pragma unroll
            for (int r = 0; r < 4; ++r) {
                const int row = m0 + mw + 16 * si + quad * 4 + r;
                C[(size_t)row * DM + col] = acc[si][sj][r];
            }
        }
    }
}

// ---------------------------------------------------------------------------
// flash attention v14 (unchanged): fragment-major K/V reg-direct loop, zero
// in-loop LDS/barriers, l via MFMA-with-ones, cvt_pk P packing. 49.3 us,
// MfmaUtil 36%, VALUBusy 31% -- latency-bound chain.
// MFMA 32x32x16 layouts: A[m=lane&31][k=(lane>>5)*8+j],
// B[k=(lane>>5)*8+j][n=lane&31], C/D col=lane&31,
// row=(reg&3)+8*(reg>>2)+4*(lane>>5)  (HW-verified m74/m101).
// ---------------------------------------------------------------------------
__global__ __launch_bounds__(512, 2) void attn_kernel(
    const unsigned short* __restrict__ Qp, const unsigned short* __restrict__ Kf,
    const unsigned short* __restrict__ Vf, unsigned short* __restrict__ Hd)
{
    __shared__ float epi[128 * 66 + 128];   // Obuf 128x66 + lbuf[128]

    const int f    = blockIdx.x;
    const int xcd  = f & 7;
    const int slot = f >> 3;            // 0..63 within XCD
    const int tile = slot & 15;         // q-tile (128 rows)
    const int bhi  = (slot >> 4) * 8 + xcd;   // 0..31
    const int b = bhi >> 3, h = bhi & 7;

    const int s0 = tile * 128;
    const size_t bh   = (size_t)(b * NH + h);
    const size_t base = bh * SEQ * DQ;

    const int t    = threadIdx.x;
    const int w    = t >> 6;      // 0..7
    const int lane = t & 63;
    const int qh   = w >> 1;      // q-quarter (rows 32qh..32qh+31 of 128)
    const int kh   = w & 1;       // kv-half within each 64-kv tile
    const int ln31 = lane & 31;
    const int lh   = lane >> 5;   // lane half

    // ---- Q B-fragments direct from global (once): B[k=d][n=q] ----
    short8 bq[4];
    {
        const unsigned short* gq = Qp + base + (size_t)(s0 + 32 * qh + ln31) * DQ + lh * 8;
        #pragma unroll
        for (int s = 0; s < 4; ++s)
            bq[s] = *(const short8*)(gq + 16 * s);
    }

    // all-ones bf16 B fragment for l row-sums
    short8 vones;
    #pragma unroll
    for (int i = 0; i < 8; ++i) vones[i] = (short)0x3F80;

    // fragment-major stream pointers: everything is base + lane*16B
    const unsigned short* pK = Kf + base + ((size_t)kh << 11) + (size_t)lane * 8;
    const unsigned short* pV = Vf + base + ((size_t)kh << 11) + (size_t)lane * 8;

    floatx16 accO[2] = {};   // partial O[32q][64dv]: a=dv-block; lane col=dv
    floatx16 accL   = {};    // partial l[32q] replicated over cols

    // ---- prologue: fragment loads for kt=0 ----
    short8 ak[4], bv[4];
    #pragma unroll
    for (int s = 0; s < 4; ++s)
        ak[s] = *(const short8*)(pK + s * 512);
    #pragma unroll
    for (int a = 0; a < 2; ++a)
        #pragma unroll
        for (int s = 0; s < 2; ++s)
            bv[a * 2 + s] = *(const short8*)(pV + a * 1024 + s * 512);

    for (int kt = 0; kt < SEQ; kt += 64) {
        // ---- S^T[32kv][32q] = K-half @ Q-quarter^T (4-chain over d=64) ----
        floatx16 z = {};
        __builtin_amdgcn_s_setprio(1);
        #pragma unroll
        for (int s = 0; s < 4; ++s)
            z = __builtin_amdgcn_mfma_f32_32x32x16_bf16(ak[s], bq[s], z, 0, 0, 0);
        __builtin_amdgcn_s_setprio(0);

        // ---- prefetch next ak ----
        const int ktn = (kt + 64 < SEQ) ? kt + 64 : kt;
        {
            const unsigned short* nK = pK + ((size_t)(ktn >> 5) << 11);
            #pragma unroll
            for (int s = 0; s < 4; ++s)
                ak[s] = *(const short8*)(nK + s * 512);
        }

        // ---- exp2 + packed bf16 convert (reg 4g+j -> kv = 8g+4lh+j) ----
        unsigned wg[4][2];
        #pragma unroll
        for (int g = 0; g < 4; ++g) {
            const float p0 = __builtin_amdgcn_exp2f(z[4 * g + 0]);
            const float p1 = __builtin_amdgcn_exp2f(z[4 * g + 1]);
            const float p2 = __builtin_amdgcn_exp2f(z[4 * g + 2]);
            const float p3 = __builtin_amdgcn_exp2f(z[4 * g + 3]);
            wg[g][0] = cvtpk(p0, p1);
            wg[g][1] = cvtpk(p2, p3);
        }

        // ---- T12: build PV A-fragments in-register via permlane32_swap ----
        const uintx2 e0 = __builtin_amdgcn_permlane32_swap(wg[0][0], wg[1][0], false, false);
        const uintx2 e1 = __builtin_amdgcn_permlane32_swap(wg[0][1], wg[1][1], false, false);
        const uintx2 e2 = __builtin_amdgcn_permlane32_swap(wg[2][0], wg[3][0], false, false);
        const uintx2 e3 = __builtin_amdgcn_permlane32_swap(wg[2][1], wg[3][1], false, false);
        uintx4 ua0, ua1;
        ua0[0] = e0[0]; ua0[1] = e1[0]; ua0[2] = e0[1]; ua0[3] = e1[1];
        ua1[0] = e2[0]; ua1[1] = e3[0]; ua1[2] = e2[1]; ua1[3] = e3[1];
        const short8 ap0 = __builtin_bit_cast(short8, ua0);
        const short8 ap1 = __builtin_bit_cast(short8, ua1);

        // ---- PV + l row-sums: accO[a] += P @ V; accL += P @ 1 ----
        __builtin_amdgcn_s_setprio(1);
        #pragma unroll
        for (int a = 0; a < 2; ++a) {
            accO[a] = __builtin_amdgcn_mfma_f32_32x32x16_bf16(ap0, bv[a * 2 + 0], accO[a], 0, 0, 0);
            accO[a] = __builtin_amdgcn_mfma_f32_32x32x16_bf16(ap1, bv[a * 2 + 1], accO[a], 0, 0, 0);
        }
        accL = __builtin_amdgcn_mfma_f32_32x32x16_bf16(ap0, vones, accL, 0, 0, 0);
        accL = __builtin_amdgcn_mfma_f32_32x32x16_bf16(ap1, vones, accL, 0, 0, 0);
        __builtin_amdgcn_s_setprio(0);

        // ---- prefetch next bv ----
        {
            const unsigned short* nV = pV + ((size_t)(ktn >> 6) << 12);
            #pragma unroll
            for (int a = 0; a < 2; ++a)
                #pragma unroll
                for (int s = 0; s < 2; ++s)
                    bv[a * 2 + s] = *(const short8*)(nV + a * 1024 + s * 512);
        }
    }

    // ---- cross-kh combine: O via LDS, l via accL (lane-local rows) ----
    float* Obuf = epi;                 // 128x66 f32
    float* lbuf = epi + 128 * 66;      // [0..127] kh0 partial l per qrow

    if (kh == 0) {
        if (ln31 == 0) {
            #pragma unroll
            for (int r = 0; r < 16; ++r) {
                const int qrow = (r & 3) + 8 * (r >> 2) + 4 * lh;
                lbuf[32 * qh + qrow] = accL[r];
            }
        }
        #pragma unroll
        for (int a = 0; a < 2; ++a)
            #pragma unroll
            for (int r = 0; r < 16; ++r) {
                const int qrow = (r & 3) + 8 * (r >> 2) + 4 * lh;
                Obuf[(32 * qh + qrow) * 66 + 32 * a + ln31] = accO[a][r];
            }
    }
    __syncthreads();

    if (kh == 1) {
        float inv[16];
        #pragma unroll
        for (int r = 0; r < 16; ++r) {
            const int qrow = (r & 3) + 8 * (r >> 2) + 4 * lh;
            inv[r] = 1.0f / (accL[r] + lbuf[32 * qh + qrow]);
        }
        #pragma unroll
        for (int a = 0; a < 2; ++a)
            #pragma unroll
            for (int r = 0; r < 16; ++r) {
                const int qrow = (r & 3) + 8 * (r >> 2) + 4 * lh;
                const float o = accO[a][r] + Obuf[(32 * qh + qrow) * 66 + 32 * a + ln31];
                Hd[base + (size_t)(s0 + 32 * qh + qrow) * DQ + 32 * a + ln31] = f2bf(o * inv[r]);
            }
    }
}

// ---------------------------------------------------------------------------
// kernel_launch
// Workspace (ushort units):
//   wt:    0        (3 x 262144)    qkv weights bf16, B^T [h*64+d][dd]
//   wo:    786432   (262144)        Wout bf16 [o][c]
//   q_ws:  1048576  (4194304)       q*QSCALE bf16 [b,h,s,d]
//   k_ws:  5242880  (4194304)       k bf16 fragment-major Kf
//   vt_ws: 9437184  (4194304)       v bf16 fragment-major Vf
//   xb:    13631488 (12582912)      X bf16 [which][8192][512] -- dead after qkv
//   h_ws:  13631488 (4194304)       heads bf16 -- OVERLAPS xb (born in attn,
//                                   after qkv finished reading xb; same-stream
//                                   kernel ordering guarantees safety)
// total 26214400 ushorts = 52.4 MB
// ---------------------------------------------------------------------------
extern "C" void kernel_launch(void* const* d_in, const int* in_sizes, int n_in,
                              void* d_out, int out_size, void* d_ws, size_t ws_size,
                              hipStream_t stream) {
    const float* xq = (const float*)d_in[0];
    const float* xk = (const float*)d_in[1];
    const float* xv = (const float*)d_in[2];
    const float* Qw = (const float*)d_in[3];
    const float* Kw = (const float*)d_in[4];
    const float* Vw = (const float*)d_in[5];
    const float* Wo = (const float*)d_in[6];
    float* out = (float*)d_out;

    unsigned short* ws = (unsigned short*)d_ws;
    unsigned short* wt    = ws;
    unsigned short* wo    = ws + (size_t)786432;
    unsigned short* q_ws  = ws + (size_t)1048576;
    unsigned short* k_ws  = ws + (size_t)5242880;
    unsigned short* vt_ws = ws + (size_t)9437184;
    unsigned short* xb    = ws + (size_t)13631488;
    unsigned short* h_ws  = ws + (size_t)13631488;   // overlaps xb (see above)

    convert_w_kernel<<<dim3(256, 4), 256, 0, stream>>>(Qw, Kw, Vw, Wo, wt, wo);
    x_convert_kernel<<<dim3(2048, 3), 256, 0, stream>>>(xq, xk, xv, xb);
    qkv_gemm_kernel<<<dim3(64, 4, 3), 256, 0, stream>>>(xb, wt, q_ws, k_ws, vt_ws);
    attn_kernel<<<dim3(512), 512, 0, stream>>>(q_ws, k_ws, vt_ws, h_ws);
    out_gemm_kernel<<<dim3(128, 4), 256, 0, stream>>>(h_ws, wo, out);
}